// Round 8
// baseline (269.780 us; speedup 1.0000x reference)
//
#include <hip/hip_runtime.h>

// CapsuleLinear dynamic routing via bf16 hi/lo MFMA, w read RAW (no w-prep).
// N=64, I=256, O=128, K=16, L=32, 3 iters.
//
// Round 8: bf16 hi+lo = 4 B/elem = same bytes as raw fp32 -> read w directly,
// split in-register (truncation: hi = top16, lo = trunc16(f - hi); residual
// exact, dropped al*bl ~ 2^-16). Kills the 64 MB w-prep kernel; ws = 1 MB
// (x fragments only). Main: batch-4i ping-pong prefetch (~256 B/lane in
// flight, 2x round 6), 512 thr / 8 waves, launch_bounds(512,2) VGPR cap 256.
//
// caps_main: grid 256 = (o 0..127) x (n-half 0..1); wave handles 32 i.
//   Per i: 3 MFMAs (al*bh + ah*bl + ah*bh ~ fp32). Fused 3-pass routing
//   (no-max softmax, logits in LDS [i][n]):
//   P0: s0 = (1/256) sum_i P_i ; P1: d=P.v0 -> lg, e=exp(d), u+=e*P -> s1
//   P2: d+=lg -> s2 -> squash -> out
// Fallback (ws too small): round-3 VALU kernel.

#define ICAPS 256
#define OCAPS 128
#define WS_NEED 1048576ull

typedef __attribute__((ext_vector_type(8))) short s16x8;
typedef __attribute__((ext_vector_type(16))) float f32x16;

union u4s8 { unsigned u[4]; s16x8 v; };

__device__ inline void split8(const float* f, s16x8& hi, s16x8& lo) {
    u4s8 H, L;
    #pragma unroll
    for (int c = 0; c < 4; ++c) {
        const unsigned u0 = __float_as_uint(f[2 * c]);
        const unsigned u1 = __float_as_uint(f[2 * c + 1]);
        H.u[c] = __builtin_amdgcn_perm(u1, u0, 0x07060302u);   // {hi16(f1),hi16(f0)}
        const float h0 = __uint_as_float(u0 & 0xFFFF0000u);
        const float h1 = __uint_as_float(u1 & 0xFFFF0000u);
        const unsigned l0 = __float_as_uint(f[2 * c] - h0);     // exact residual
        const unsigned l1 = __float_as_uint(f[2 * c + 1] - h1);
        L.u[c] = __builtin_amdgcn_perm(l1, l0, 0x07060302u);
    }
    hi = H.v; lo = L.v;
}

// ---------------- x prep: fp32 -> bf16 hi/lo fragments (1 MB) ----------------
__global__ __launch_bounds__(512)
void caps_prep_x(const float* __restrict__ x, unsigned char* __restrict__ ws) {
    const int wv = threadIdx.x >> 6, lane = threadIdx.x & 63;
    const int id = blockIdx.x * 8 + wv;          // 0..511 = nh*256 + i
    const int nh = id >> 8, i = id & 255;
    const int np = lane & 31, kb = (lane >> 5) * 8;
    const float* src = x + ((size_t)(nh * 32 + np) * ICAPS + i) * 16 + kb;
    float f[8];
    const float4 a = *(const float4*)src;
    const float4 b = *(const float4*)(src + 4);
    f[0] = a.x; f[1] = a.y; f[2] = a.z; f[3] = a.w;
    f[4] = b.x; f[5] = b.y; f[6] = b.z; f[7] = b.w;
    s16x8 hi, lo;
    split8(f, hi, lo);
    s16x8* XC = (s16x8*)ws;
    const size_t idx = ((size_t)id * 64 + lane) * 2;
    XC[idx] = hi;
    XC[idx + 1] = lo;
}

// ---------------- main: MFMA routing, raw-w ----------------
__global__ __launch_bounds__(512, 2)
void caps_main(const float* __restrict__ w, const unsigned char* __restrict__ ws,
               float* __restrict__ out) {
    __shared__ float lg[ICAPS * 32];      // [i][n] 32 KB
    __shared__ float slab[8 * 1280];      // per-wave u partials (lane stride 20)
    __shared__ float svv[32 * 33];        // s then v
    __shared__ float zz[8 * 32];
    __shared__ float zinv[32];

    const int t = threadIdx.x, wv = t >> 6, lane = t & 63;
    const int o = blockIdx.x & 127, nh = blockIdx.x >> 7;   // o-pairs share an XCD
    const int n = lane & 31, half = lane >> 5;

    // raw w fragment source: lane reads w[o][i][kb+j][l], j=0..7 (stride 32 floats)
    const float* wg = w + (size_t)o * (ICAPS * 512) + (lane >> 5) * 256 + (lane & 31);
    // prepped x: per (i,lane) 2 consecutive s16x8 (hi,lo)
    const s16x8* Xp = (const s16x8*)ws + ((size_t)nh * ICAPS * 64 + lane) * 2;

    float vr[16];
    const int ibase = wv * 32;

    auto LOADB = [&](int ib, float (&Wb)[4][8], s16x8 (&Xb)[4][2]) {
        #pragma unroll
        for (int j = 0; j < 4; ++j) {
            const float* wp = wg + (size_t)(ib + j) * 512;
            #pragma unroll
            for (int k = 0; k < 8; ++k) Wb[j][k] = wp[k * 32];
            Xb[j][0] = Xp[(size_t)(ib + j) * 128];
            Xb[j][1] = Xp[(size_t)(ib + j) * 128 + 1];
        }
    };

    for (int pass = 0; pass < 3; ++pass) {
        float uacc[16];
        #pragma unroll
        for (int r = 0; r < 16; ++r) uacc[r] = 0.f;
        float z = 0.f;

        float W0[4][8], W1[4][8];
        s16x8 X0[4][2], X1[4][2];
        f32x16 Pa = {}, Pb = {};

        auto PROC0 = [&](float (&Wb)[4][8], s16x8 (&Xb)[4][2]) {
            #pragma unroll
            for (int j = 0; j < 4; ++j) {
                s16x8 ah, al;
                split8(Wb[j], ah, al);
                if (j & 1) {
                    Pb = __builtin_amdgcn_mfma_f32_32x32x16_bf16(al, Xb[j][0], Pb, 0, 0, 0);
                    Pb = __builtin_amdgcn_mfma_f32_32x32x16_bf16(ah, Xb[j][1], Pb, 0, 0, 0);
                    Pb = __builtin_amdgcn_mfma_f32_32x32x16_bf16(ah, Xb[j][0], Pb, 0, 0, 0);
                } else {
                    Pa = __builtin_amdgcn_mfma_f32_32x32x16_bf16(al, Xb[j][0], Pa, 0, 0, 0);
                    Pa = __builtin_amdgcn_mfma_f32_32x32x16_bf16(ah, Xb[j][1], Pa, 0, 0, 0);
                    Pa = __builtin_amdgcn_mfma_f32_32x32x16_bf16(ah, Xb[j][0], Pa, 0, 0, 0);
                }
            }
        };

        auto PROC12 = [&](int ib, float (&Wb)[4][8], s16x8 (&Xb)[4][2]) {
            #pragma unroll
            for (int j = 0; j < 4; ++j) {
                s16x8 ah, al;
                split8(Wb[j], ah, al);
                f32x16 P = {};
                P = __builtin_amdgcn_mfma_f32_32x32x16_bf16(al, Xb[j][0], P, 0, 0, 0);
                P = __builtin_amdgcn_mfma_f32_32x32x16_bf16(ah, Xb[j][1], P, 0, 0, 0);
                P = __builtin_amdgcn_mfma_f32_32x32x16_bf16(ah, Xb[j][0], P, 0, 0, 0);
                const int i = ib + j;
                float da = P[0] * vr[0];
                float db = P[8] * vr[8];
                #pragma unroll
                for (int r = 1; r < 8; ++r) {
                    da = fmaf(P[r], vr[r], da);
                    db = fmaf(P[r + 8], vr[r + 8], db);
                }
                float d = da + db;
                d += __shfl_xor(d, 32);                 // combine l-halves
                if (pass == 1) {
                    if (half == 0) lg[i * 32 + n] = d;  // store logits for pass 2
                } else {
                    d += lg[i * 32 + n];
                }
                const float e = __expf(d);
                z += e;
                #pragma unroll
                for (int r = 0; r < 16; ++r) uacc[r] = fmaf(e, P[r], uacc[r]);
            }
        };

        LOADB(ibase, W0, X0);
        for (int bb = 0; bb < 8; bb += 2) {
            if (bb + 1 < 8) LOADB(ibase + (bb + 1) * 4, W1, X1);
            if (pass == 0) PROC0(W0, X0); else PROC12(ibase + bb * 4, W0, X0);
            if (bb + 2 < 8) LOADB(ibase + (bb + 2) * 4, W0, X0);
            if (bb + 1 < 8) {
                if (pass == 0) PROC0(W1, X1); else PROC12(ibase + (bb + 1) * 4, W1, X1);
            }
        }
        if (pass == 0) {
            #pragma unroll
            for (int r = 0; r < 16; ++r) uacc[r] = Pa[r] + Pb[r];
        }

        // ---- cross-wave reduce of u (and z) over 8 waves ----
        #pragma unroll
        for (int c = 0; c < 4; ++c)
            *(float4*)(&slab[wv * 1280 + lane * 20 + c * 4]) =
                make_float4(uacc[4 * c], uacc[4 * c + 1], uacc[4 * c + 2], uacc[4 * c + 3]);
        if (pass > 0 && half == 0) zz[wv * 32 + n] = z;
        __syncthreads();

        #pragma unroll
        for (int hh = 0; hh < 2; ++hh) {
            const int e = t + hh * 512;
            const int lw = e >> 4, r = e & 15;
            float s = 0.f;
            #pragma unroll
            for (int w8 = 0; w8 < 8; ++w8) s += slab[w8 * 1280 + lw * 20 + r];
            const int nn = lw & 31, ll = (r & 3) + 8 * (r >> 2) + 4 * (lw >> 5);
            svv[nn * 33 + ll] = s;
        }
        if (t < 32) {
            if (pass == 0) zinv[t] = 1.0f / 256.0f;
            else {
                float zs = 0.f;
                #pragma unroll
                for (int w8 = 0; w8 < 8; ++w8) zs += zz[w8 * 32 + t];
                zinv[t] = 1.0f / zs;
            }
        }
        __syncthreads();

        // ---- squash (and output on last pass) ----
        {
            const int nq = t >> 4, sub = t & 15;
            const float a = svv[nq * 33 + sub] * zinv[nq];
            const float b = svv[nq * 33 + sub + 16] * zinv[nq];
            float sq = a * a + b * b;
            #pragma unroll
            for (int m = 1; m < 16; m <<= 1) sq += __shfl_xor(sq, m, 16);
            const float sc = sqrtf(sq) / (1.0f + sq);
            if (pass == 2) {
                const int ng = nh * 32 + nq;
                out[((size_t)ng * OCAPS + o) * 32 + sub] = a * sc;
                out[((size_t)ng * OCAPS + o) * 32 + sub + 16] = b * sc;
            } else {
                svv[nq * 33 + sub] = a * sc;
                svv[nq * 33 + sub + 16] = b * sc;
            }
        }
        if (pass < 2) {
            __syncthreads();
            #pragma unroll
            for (int r = 0; r < 16; ++r) {
                const int l = (r & 3) + 8 * (r >> 2) + 4 * half;
                vr[r] = svv[n * 33 + l];
            }
        }
    }
}

// ---------------- fallback (round-3 kernel, no ws needed) ----------------
#define KLEN  16
#define LLEN  32
#define TN    16
#define LGS   257
#define XROW  20
#define XIST  (TN * XROW + 4)
#define SVS   33
#define RBS   33
#define NSTG  32
#define NSTEP (ICAPS / NSTG)

__global__ __launch_bounds__(512, 2)
void caps_route_fb(const float* __restrict__ xg_all,
                   const float* __restrict__ wg_all,
                   float* __restrict__ out) {
    __shared__ float lg[TN * LGS];
    __shared__ float xt[NSTG * XIST];
    __shared__ float sv[TN * SVS];
    __shared__ float zz[8][TN];
    __shared__ float zinv[TN];

    const int t   = threadIdx.x;
    const int o   = blockIdx.x & 127;
    const int n0  = (blockIdx.x >> 7) * TN;
    const int isp = t >> 4;
    const int lb  = (t >> 2) & 3;
    const int nb  = t & 3;
    const int l0  = lb * 8;

    const float* xg = xg_all + (size_t)n0 * ICAPS * KLEN;
    const float* wg = wg_all + (size_t)o * ICAPS * KLEN * LLEN;

    for (int pass = 0; pass < 3; ++pass) {
        float u[4][8];
        float zq[4] = {0.f, 0.f, 0.f, 0.f};
        #pragma unroll
        for (int q = 0; q < 4; ++q)
            #pragma unroll
            for (int r = 0; r < 8; ++r) u[q][r] = 0.f;

        for (int st = 0; st < NSTEP; ++st) {
            const int i0 = st * NSTG;
            __syncthreads();
            #pragma unroll
            for (int j = 0; j < 4; ++j) {
                const int g   = j * 512 + t;
                const int nn  = g >> 7;
                const int rem = g & 127;
                const int il  = rem >> 2;
                const int k4c = rem & 3;
                *(float4*)(&xt[il * XIST + nn * XROW + k4c * 4]) =
                    *(const float4*)(xg + (size_t)(nn * ICAPS + i0 + il) * KLEN + k4c * 4);
            }
            __syncthreads();

            const int i = i0 + isp;
            const float* wp = wg + (size_t)i * (KLEN * LLEN) + l0;
            const float* xp = &xt[isp * XIST];
            float P[4][8];
            #pragma unroll
            for (int q = 0; q < 4; ++q)
                #pragma unroll
                for (int r = 0; r < 8; ++r) P[q][r] = 0.f;

            #pragma unroll
            for (int k4 = 0; k4 < 4; ++k4) {
                float xq[4][4];
                #pragma unroll
                for (int q = 0; q < 4; ++q)
                    *(float4*)(&xq[q][0]) = *(const float4*)(xp + (nb + 4 * q) * XROW + k4 * 4);
                #pragma unroll
                for (int kk = 0; kk < 4; ++kk) {
                    const int k = k4 * 4 + kk;
                    const float4 wa = *(const float4*)(wp + k * LLEN);
                    const float4 wb = *(const float4*)(wp + k * LLEN + 4);
                    #pragma unroll
                    for (int q = 0; q < 4; ++q) {
                        const float xv = xq[q][kk];
                        P[q][0] = fmaf(xv, wa.x, P[q][0]);
                        P[q][1] = fmaf(xv, wa.y, P[q][1]);
                        P[q][2] = fmaf(xv, wa.z, P[q][2]);
                        P[q][3] = fmaf(xv, wa.w, P[q][3]);
                        P[q][4] = fmaf(xv, wb.x, P[q][4]);
                        P[q][5] = fmaf(xv, wb.y, P[q][5]);
                        P[q][6] = fmaf(xv, wb.z, P[q][6]);
                        P[q][7] = fmaf(xv, wb.w, P[q][7]);
                    }
                }
            }

            if (pass == 0) {
                #pragma unroll
                for (int q = 0; q < 4; ++q)
                    #pragma unroll
                    for (int r = 0; r < 8; ++r) u[q][r] += P[q][r];
            } else {
                #pragma unroll
                for (int q = 0; q < 4; ++q) {
                    const float* vp = &sv[(nb + 4 * q) * SVS + l0];
                    float d = P[q][0] * vp[0] + P[q][1] * vp[1] + P[q][2] * vp[2] + P[q][3] * vp[3]
                            + P[q][4] * vp[4] + P[q][5] * vp[5] + P[q][6] * vp[6] + P[q][7] * vp[7];
                    d += __shfl_xor(d, 4);
                    d += __shfl_xor(d, 8);
                    float lnew = d;
                    if (pass == 2) lnew += lg[(nb + 4 * q) * LGS + i];
                    else if (lb == 0) lg[(nb + 4 * q) * LGS + i] = lnew;
                    const float e = __expf(lnew);
                    zq[q] += e;
                    #pragma unroll
                    for (int r = 0; r < 8; ++r) u[q][r] = fmaf(e, P[q][r], u[q][r]);
                }
            }
        }

        #pragma unroll
        for (int q = 0; q < 4; ++q) {
            #pragma unroll
            for (int r = 0; r < 8; ++r) {
                float v = u[q][r];
                v += __shfl_xor(v, 16);
                v += __shfl_xor(v, 32);
                u[q][r] = v;
            }
            float zv = zq[q];
            zv += __shfl_xor(zv, 16);
            zv += __shfl_xor(zv, 32);
            zq[q] = zv;
        }
        __syncthreads();
        {
            const int wvv = t >> 6, lane = t & 63;
            if (lane < 16) {
                float* rb = &xt[wvv * (16 * RBS) + lane * RBS];
                #pragma unroll
                for (int q = 0; q < 4; ++q)
                    #pragma unroll
                    for (int r = 0; r < 8; ++r) rb[q * 8 + r] = u[q][r];
            }
            if (pass > 0 && lane < 4) {
                #pragma unroll
                for (int q = 0; q < 4; ++q) zz[wvv][lane + 4 * q] = zq[q];
            }
        }
        __syncthreads();
        {
            const int low4 = t >> 5, qr = t & 31;
            const int qq = qr >> 3, rr = qr & 7;
            const int lbb = low4 >> 2, nbb = low4 & 3;
            float ssum = 0.f;
            #pragma unroll
            for (int w8 = 0; w8 < 8; ++w8) ssum += xt[w8 * (16 * RBS) + low4 * RBS + qr];
            sv[(nbb + 4 * qq) * SVS + lbb * 8 + rr] = ssum;
        }
        if (t < TN) {
            if (pass == 0) zinv[t] = 1.0f / 256.0f;
            else {
                float zs = 0.f;
                #pragma unroll
                for (int w8 = 0; w8 < 8; ++w8) zs += zz[w8][t];
                zinv[t] = 1.0f / zs;
            }
        }
        __syncthreads();
        {
            const int nn = t >> 5, l = t & 31;
            const float val = sv[nn * SVS + l] * zinv[nn];
            float sq = val * val;
            #pragma unroll
            for (int m = 1; m < 32; m <<= 1) sq += __shfl_xor(sq, m, 32);
            const float sc = sqrtf(sq) / (1.0f + sq);
            if (pass == 2)
                out[((size_t)(n0 + nn) * OCAPS + o) * LLEN + l] = val * sc;
            else
                sv[nn * SVS + l] = val * sc;
        }
    }
}

extern "C" void kernel_launch(void* const* d_in, const int* in_sizes, int n_in,
                              void* d_out, int out_size, void* d_ws, size_t ws_size,
                              hipStream_t stream) {
    const float* x = (const float*)d_in[0];   // [64,256,16]
    const float* w = (const float*)d_in[1];   // [128,256,16,32]
    float* outp = (float*)d_out;              // [64,128,32]
    if (ws_size >= WS_NEED) {
        caps_prep_x<<<dim3(64), dim3(512), 0, stream>>>(x, (unsigned char*)d_ws);
        caps_main<<<dim3(256), dim3(512), 0, stream>>>(w, (const unsigned char*)d_ws, outp);
    } else {
        caps_route_fb<<<dim3(512), dim3(512), 0, stream>>>(x, w, outp);
    }
}

// Round 9
// 149.291 us; speedup vs baseline: 1.8071x; 1.8071x over previous
//
#include <hip/hip_runtime.h>

// CapsuleLinear dynamic routing via bf16 hi/lo MFMA, w read RAW with
// in-register RNE split (no w-prep kernel). N=64, I=256, O=128, K=16, L=32.
//
// Round 9 = round-6 main structure (proven 50 us) + raw-W:
//   hi = RNE-bf16(f); lo = RNE-bf16(f - hi)  (residual exact in fp32)
//   -> identical numerics to round 4/6 (absmax 1.95e-3).
// Batch-2 double-buffered prefetch ONLY (W raw 32 regs + X 16 regs buffers)
// to stay under the VGPR cliff that killed rounds 7/8 (watch WRITE_SIZE!).
//
// caps_prep_x: x fp32 -> bf16 hi/lo fragments, 1 MB in ws.
// caps_main: grid 256 = (o 0..127) x (n-half 0..1), 512 thr, 8 waves x 32 i.
//   Per i: 3 MFMAs (al*bh + ah*bl + ah*bh ~ fp32). Fused 3-pass routing
//   (no-max softmax, logits in LDS [i][n]):
//   P0: s0 = (1/256) sum_i P_i ; P1: d=P.v0 -> lg, e=exp(d), u+=e*P -> s1
//   P2: d+=lg -> s2 -> squash -> out
// Fallback (ws too small): round-3 VALU kernel.

#define ICAPS 256
#define OCAPS 128
#define WS_NEED 1048576ull

typedef __attribute__((ext_vector_type(8))) short s16x8;
typedef __attribute__((ext_vector_type(16))) float f32x16;

union u4s8 { unsigned u[4]; s16x8 v; };

__device__ inline unsigned rne_adj(unsigned u) {       // bits + rounding increment
    return u + 0x7FFFu + ((u >> 16) & 1u);
}

// RNE hi/lo split of 8 fp32 -> two packed s16x8 (bf16 pairs), R4 numerics.
__device__ inline void split8(const float* f, s16x8& hi, s16x8& lo) {
    u4s8 H, L;
    #pragma unroll
    for (int c = 0; c < 4; ++c) {
        const unsigned u0 = __float_as_uint(f[2 * c]);
        const unsigned u1 = __float_as_uint(f[2 * c + 1]);
        const unsigned r0 = rne_adj(u0), r1 = rne_adj(u1);
        H.u[c] = __builtin_amdgcn_perm(r1, r0, 0x07060302u);   // {hi16(r1),hi16(r0)}
        const float h0 = __uint_as_float(r0 & 0xFFFF0000u);
        const float h1 = __uint_as_float(r1 & 0xFFFF0000u);
        const unsigned l0 = rne_adj(__float_as_uint(f[2 * c] - h0));      // exact resid
        const unsigned l1 = rne_adj(__float_as_uint(f[2 * c + 1] - h1));  // then RNE
        L.u[c] = __builtin_amdgcn_perm(l1, l0, 0x07060302u);
    }
    hi = H.v; lo = L.v;
}

// ---------------- x prep: fp32 -> bf16 hi/lo fragments (1 MB) ----------------
__global__ __launch_bounds__(512)
void caps_prep_x(const float* __restrict__ x, unsigned char* __restrict__ ws) {
    const int wv = threadIdx.x >> 6, lane = threadIdx.x & 63;
    const int id = blockIdx.x * 8 + wv;          // 0..511 = nh*256 + i
    const int nh = id >> 8, i = id & 255;
    const int np = lane & 31, kb = (lane >> 5) * 8;
    const float* src = x + ((size_t)(nh * 32 + np) * ICAPS + i) * 16 + kb;
    float f[8];
    const float4 a = *(const float4*)src;
    const float4 b = *(const float4*)(src + 4);
    f[0] = a.x; f[1] = a.y; f[2] = a.z; f[3] = a.w;
    f[4] = b.x; f[5] = b.y; f[6] = b.z; f[7] = b.w;
    s16x8 hi, lo;
    split8(f, hi, lo);
    s16x8* XC = (s16x8*)ws;
    const size_t idx = ((size_t)id * 64 + lane) * 2;
    XC[idx] = hi;
    XC[idx + 1] = lo;
}

// ---------------- main: MFMA routing, raw-w in-register split ----------------
__global__ __launch_bounds__(512)
void caps_main(const float* __restrict__ w, const unsigned char* __restrict__ ws,
               float* __restrict__ out) {
    __shared__ float lg[ICAPS * 32];      // [i][n] 32 KB
    __shared__ float slab[8 * 1280];      // per-wave u partials (lane stride 20)
    __shared__ float svv[32 * 33];        // s then v
    __shared__ float zz[8 * 32];
    __shared__ float zinv[32];

    const int t = threadIdx.x, wv = t >> 6, lane = t & 63;
    const int o = blockIdx.x & 127, nh = blockIdx.x >> 7;   // o-pairs share an XCD
    const int n = lane & 31, half = lane >> 5;

    // raw w: lane reads w[o][i][kb+j][l], j=0..7 (dword loads, 128B/segment/half)
    const float* wg = w + (size_t)o * (ICAPS * 512) + (lane >> 5) * 256 + (lane & 31);
    // prepped x: per (i,lane) 2 consecutive s16x8 (hi,lo); stride per i = 128
    const s16x8* Xp = (const s16x8*)ws + ((size_t)nh * ICAPS * 64 + lane) * 2;

    float vr[16];
    const int ibase = wv * 32;

    for (int pass = 0; pass < 3; ++pass) {
        float uacc[16];
        #pragma unroll
        for (int r = 0; r < 16; ++r) uacc[r] = 0.f;
        float z = 0.f;

        // batch-2 double buffers: raw W (2x8 fp32) + X frags (2x2 s16x8)
        float W0[2][8], W1[2][8];
        s16x8 X0[2][2], X1[2][2];
        #pragma unroll
        for (int j = 0; j < 2; ++j) {
            const float* wp = wg + (size_t)(ibase + j) * 512;
            #pragma unroll
            for (int k = 0; k < 8; ++k) W0[j][k] = wp[k * 32];
            X0[j][0] = Xp[(size_t)(ibase + j) * 128];
            X0[j][1] = Xp[(size_t)(ibase + j) * 128 + 1];
        }

        f32x16 Pa = {}, Pb = {};

        for (int bb = 0; bb < 16; ++bb) {
            // prefetch next batch into the other buffer
            if (bb < 15) {
                const int inext = ibase + (bb + 1) * 2;
                #pragma unroll
                for (int j = 0; j < 2; ++j) {
                    const float* wp = wg + (size_t)(inext + j) * 512;
                    #pragma unroll
                    for (int k = 0; k < 8; ++k) W1[j][k] = wp[k * 32];
                    X1[j][0] = Xp[(size_t)(inext + j) * 128];
                    X1[j][1] = Xp[(size_t)(inext + j) * 128 + 1];
                }
            }

            if (pass == 0) {
                #pragma unroll
                for (int j = 0; j < 2; ++j) {
                    s16x8 ah, al;
                    split8(W0[j], ah, al);
                    if (j == 0) {
                        Pa = __builtin_amdgcn_mfma_f32_32x32x16_bf16(al, X0[j][0], Pa, 0, 0, 0);
                        Pa = __builtin_amdgcn_mfma_f32_32x32x16_bf16(ah, X0[j][1], Pa, 0, 0, 0);
                        Pa = __builtin_amdgcn_mfma_f32_32x32x16_bf16(ah, X0[j][0], Pa, 0, 0, 0);
                    } else {
                        Pb = __builtin_amdgcn_mfma_f32_32x32x16_bf16(al, X0[j][0], Pb, 0, 0, 0);
                        Pb = __builtin_amdgcn_mfma_f32_32x32x16_bf16(ah, X0[j][1], Pb, 0, 0, 0);
                        Pb = __builtin_amdgcn_mfma_f32_32x32x16_bf16(ah, X0[j][0], Pb, 0, 0, 0);
                    }
                }
            } else {
                #pragma unroll
                for (int j = 0; j < 2; ++j) {
                    s16x8 ah, al;
                    split8(W0[j], ah, al);
                    f32x16 P = {};
                    P = __builtin_amdgcn_mfma_f32_32x32x16_bf16(al, X0[j][0], P, 0, 0, 0);
                    P = __builtin_amdgcn_mfma_f32_32x32x16_bf16(ah, X0[j][1], P, 0, 0, 0);
                    P = __builtin_amdgcn_mfma_f32_32x32x16_bf16(ah, X0[j][0], P, 0, 0, 0);
                    const int i = ibase + bb * 2 + j;
                    float da = P[0] * vr[0];
                    float db = P[8] * vr[8];
                    #pragma unroll
                    for (int r = 1; r < 8; ++r) {
                        da = fmaf(P[r], vr[r], da);
                        db = fmaf(P[r + 8], vr[r + 8], db);
                    }
                    float d = da + db;
                    d += __shfl_xor(d, 32);                 // combine l-halves
                    if (pass == 1) {
                        if (half == 0) lg[i * 32 + n] = d;  // store logits for pass 2
                    } else {
                        d += lg[i * 32 + n];
                    }
                    const float e = __expf(d);
                    z += e;
                    #pragma unroll
                    for (int r = 0; r < 16; ++r) uacc[r] = fmaf(e, P[r], uacc[r]);
                }
            }

            if (bb < 15) {
                #pragma unroll
                for (int j = 0; j < 2; ++j) {
                    #pragma unroll
                    for (int k = 0; k < 8; ++k) W0[j][k] = W1[j][k];
                    X0[j][0] = X1[j][0];
                    X0[j][1] = X1[j][1];
                }
            }
        }
        if (pass == 0) {
            #pragma unroll
            for (int r = 0; r < 16; ++r) uacc[r] = Pa[r] + Pb[r];
        }

        // ---- cross-wave reduce of u (and z) over 8 waves ----
        #pragma unroll
        for (int c = 0; c < 4; ++c)
            *(float4*)(&slab[wv * 1280 + lane * 20 + c * 4]) =
                make_float4(uacc[4 * c], uacc[4 * c + 1], uacc[4 * c + 2], uacc[4 * c + 3]);
        if (pass > 0 && half == 0) zz[wv * 32 + n] = z;
        __syncthreads();

        #pragma unroll
        for (int hh = 0; hh < 2; ++hh) {
            const int e = t + hh * 512;
            const int lw = e >> 4, r = e & 15;
            float s = 0.f;
            #pragma unroll
            for (int w8 = 0; w8 < 8; ++w8) s += slab[w8 * 1280 + lw * 20 + r];
            const int nn = lw & 31, ll = (r & 3) + 8 * (r >> 2) + 4 * (lw >> 5);
            svv[nn * 33 + ll] = s;
        }
        if (t < 32) {
            if (pass == 0) zinv[t] = 1.0f / 256.0f;
            else {
                float zs = 0.f;
                #pragma unroll
                for (int w8 = 0; w8 < 8; ++w8) zs += zz[w8 * 32 + t];
                zinv[t] = 1.0f / zs;
            }
        }
        __syncthreads();

        // ---- squash (and output on last pass) ----
        {
            const int nq = t >> 4, sub = t & 15;
            const float a = svv[nq * 33 + sub] * zinv[nq];
            const float b = svv[nq * 33 + sub + 16] * zinv[nq];
            float sq = a * a + b * b;
            #pragma unroll
            for (int m = 1; m < 16; m <<= 1) sq += __shfl_xor(sq, m, 16);
            const float sc = sqrtf(sq) / (1.0f + sq);
            if (pass == 2) {
                const int ng = nh * 32 + nq;
                out[((size_t)ng * OCAPS + o) * 32 + sub] = a * sc;
                out[((size_t)ng * OCAPS + o) * 32 + sub + 16] = b * sc;
            } else {
                svv[nq * 33 + sub] = a * sc;
                svv[nq * 33 + sub + 16] = b * sc;
            }
        }
        if (pass < 2) {
            __syncthreads();
            #pragma unroll
            for (int r = 0; r < 16; ++r) {
                const int l = (r & 3) + 8 * (r >> 2) + 4 * half;
                vr[r] = svv[n * 33 + l];
            }
        }
    }
}

// ---------------- fallback (round-3 kernel, no ws needed) ----------------
#define KLEN  16
#define LLEN  32
#define TN    16
#define LGS   257
#define XROW  20
#define XIST  (TN * XROW + 4)
#define SVS   33
#define RBS   33
#define NSTG  32
#define NSTEP (ICAPS / NSTG)

__global__ __launch_bounds__(512, 2)
void caps_route_fb(const float* __restrict__ xg_all,
                   const float* __restrict__ wg_all,
                   float* __restrict__ out) {
    __shared__ float lg[TN * LGS];
    __shared__ float xt[NSTG * XIST];
    __shared__ float sv[TN * SVS];
    __shared__ float zz[8][TN];
    __shared__ float zinv[TN];

    const int t   = threadIdx.x;
    const int o   = blockIdx.x & 127;
    const int n0  = (blockIdx.x >> 7) * TN;
    const int isp = t >> 4;
    const int lb  = (t >> 2) & 3;
    const int nb  = t & 3;
    const int l0  = lb * 8;

    const float* xg = xg_all + (size_t)n0 * ICAPS * KLEN;
    const float* wg = wg_all + (size_t)o * ICAPS * KLEN * LLEN;

    for (int pass = 0; pass < 3; ++pass) {
        float u[4][8];
        float zq[4] = {0.f, 0.f, 0.f, 0.f};
        #pragma unroll
        for (int q = 0; q < 4; ++q)
            #pragma unroll
            for (int r = 0; r < 8; ++r) u[q][r] = 0.f;

        for (int st = 0; st < NSTEP; ++st) {
            const int i0 = st * NSTG;
            __syncthreads();
            #pragma unroll
            for (int j = 0; j < 4; ++j) {
                const int g   = j * 512 + t;
                const int nn  = g >> 7;
                const int rem = g & 127;
                const int il  = rem >> 2;
                const int k4c = rem & 3;
                *(float4*)(&xt[il * XIST + nn * XROW + k4c * 4]) =
                    *(const float4*)(xg + (size_t)(nn * ICAPS + i0 + il) * KLEN + k4c * 4);
            }
            __syncthreads();

            const int i = i0 + isp;
            const float* wp = wg + (size_t)i * (KLEN * LLEN) + l0;
            const float* xp = &xt[isp * XIST];
            float P[4][8];
            #pragma unroll
            for (int q = 0; q < 4; ++q)
                #pragma unroll
                for (int r = 0; r < 8; ++r) P[q][r] = 0.f;

            #pragma unroll
            for (int k4 = 0; k4 < 4; ++k4) {
                float xq[4][4];
                #pragma unroll
                for (int q = 0; q < 4; ++q)
                    *(float4*)(&xq[q][0]) = *(const float4*)(xp + (nb + 4 * q) * XROW + k4 * 4);
                #pragma unroll
                for (int kk = 0; kk < 4; ++kk) {
                    const int k = k4 * 4 + kk;
                    const float4 wa = *(const float4*)(wp + k * LLEN);
                    const float4 wb = *(const float4*)(wp + k * LLEN + 4);
                    #pragma unroll
                    for (int q = 0; q < 4; ++q) {
                        const float xv = xq[q][kk];
                        P[q][0] = fmaf(xv, wa.x, P[q][0]);
                        P[q][1] = fmaf(xv, wa.y, P[q][1]);
                        P[q][2] = fmaf(xv, wa.z, P[q][2]);
                        P[q][3] = fmaf(xv, wa.w, P[q][3]);
                        P[q][4] = fmaf(xv, wb.x, P[q][4]);
                        P[q][5] = fmaf(xv, wb.y, P[q][5]);
                        P[q][6] = fmaf(xv, wb.z, P[q][6]);
                        P[q][7] = fmaf(xv, wb.w, P[q][7]);
                    }
                }
            }

            if (pass == 0) {
                #pragma unroll
                for (int q = 0; q < 4; ++q)
                    #pragma unroll
                    for (int r = 0; r < 8; ++r) u[q][r] += P[q][r];
            } else {
                #pragma unroll
                for (int q = 0; q < 4; ++q) {
                    const float* vp = &sv[(nb + 4 * q) * SVS + l0];
                    float d = P[q][0] * vp[0] + P[q][1] * vp[1] + P[q][2] * vp[2] + P[q][3] * vp[3]
                            + P[q][4] * vp[4] + P[q][5] * vp[5] + P[q][6] * vp[6] + P[q][7] * vp[7];
                    d += __shfl_xor(d, 4);
                    d += __shfl_xor(d, 8);
                    float lnew = d;
                    if (pass == 2) lnew += lg[(nb + 4 * q) * LGS + i];
                    else if (lb == 0) lg[(nb + 4 * q) * LGS + i] = lnew;
                    const float e = __expf(lnew);
                    zq[q] += e;
                    #pragma unroll
                    for (int r = 0; r < 8; ++r) u[q][r] = fmaf(e, P[q][r], u[q][r]);
                }
            }
        }

        #pragma unroll
        for (int q = 0; q < 4; ++q) {
            #pragma unroll
            for (int r = 0; r < 8; ++r) {
                float v = u[q][r];
                v += __shfl_xor(v, 16);
                v += __shfl_xor(v, 32);
                u[q][r] = v;
            }
            float zv = zq[q];
            zv += __shfl_xor(zv, 16);
            zv += __shfl_xor(zv, 32);
            zq[q] = zv;
        }
        __syncthreads();
        {
            const int wvv = t >> 6, lane = t & 63;
            if (lane < 16) {
                float* rb = &xt[wvv * (16 * RBS) + lane * RBS];
                #pragma unroll
                for (int q = 0; q < 4; ++q)
                    #pragma unroll
                    for (int r = 0; r < 8; ++r) rb[q * 8 + r] = u[q][r];
            }
            if (pass > 0 && lane < 4) {
                #pragma unroll
                for (int q = 0; q < 4; ++q) zz[wvv][lane + 4 * q] = zq[q];
            }
        }
        __syncthreads();
        {
            const int low4 = t >> 5, qr = t & 31;
            const int qq = qr >> 3, rr = qr & 7;
            const int lbb = low4 >> 2, nbb = low4 & 3;
            float ssum = 0.f;
            #pragma unroll
            for (int w8 = 0; w8 < 8; ++w8) ssum += xt[w8 * (16 * RBS) + low4 * RBS + qr];
            sv[(nbb + 4 * qq) * SVS + lbb * 8 + rr] = ssum;
        }
        if (t < TN) {
            if (pass == 0) zinv[t] = 1.0f / 256.0f;
            else {
                float zs = 0.f;
                #pragma unroll
                for (int w8 = 0; w8 < 8; ++w8) zs += zz[w8][t];
                zinv[t] = 1.0f / zs;
            }
        }
        __syncthreads();
        {
            const int nn = t >> 5, l = t & 31;
            const float val = sv[nn * SVS + l] * zinv[nn];
            float sq = val * val;
            #pragma unroll
            for (int m = 1; m < 32; m <<= 1) sq += __shfl_xor(sq, m, 32);
            const float sc = sqrtf(sq) / (1.0f + sq);
            if (pass == 2)
                out[((size_t)(n0 + nn) * OCAPS + o) * LLEN + l] = val * sc;
            else
                sv[nn * SVS + l] = val * sc;
        }
    }
}

extern "C" void kernel_launch(void* const* d_in, const int* in_sizes, int n_in,
                              void* d_out, int out_size, void* d_ws, size_t ws_size,
                              hipStream_t stream) {
    const float* x = (const float*)d_in[0];   // [64,256,16]
    const float* w = (const float*)d_in[1];   // [128,256,16,32]
    float* outp = (float*)d_out;              // [64,128,32]
    if (ws_size >= WS_NEED) {
        caps_prep_x<<<dim3(64), dim3(512), 0, stream>>>(x, (unsigned char*)d_ws);
        caps_main<<<dim3(256), dim3(512), 0, stream>>>(w, (const unsigned char*)d_ws, outp);
    } else {
        caps_route_fb<<<dim3(512), dim3(512), 0, stream>>>(x, w, outp);
    }
}

// Round 10
// 143.552 us; speedup vs baseline: 1.8793x; 1.0400x over previous
//
#include <hip/hip_runtime.h>

// CapsuleLinear dynamic routing via bf16 hi/lo MFMA. N=64, I=256, O=128, K=16, L=32.
//
// Round 10 = R6's proven 50us main (prepped fragments, coalesced 16B loads)
// + bandwidth-bound prep (R6's prep burned ~45us on strided dword reads):
//   prep reads each 2KB w-tile coalesced (float4), transposes via per-wave
//   LDS (KPAD=20 keeps b128 alignment), RNE hi/lo split, stores fragments in
//   BLOCK layout (hi at tile*128+lane, lo at +64) -> stores and main loads
//   are all full 1KB coalesced segments. x-prep fused (last 64 blocks).
//
// caps_main: grid 256 = (o 0..127) x (n-half 0..1), 512 thr, 8 waves x 32 i.
//   Per i: 3 MFMAs (al*bh + ah*bl + ah*bh ~ fp32, err ~2^-17). Batch-2
//   ping-pong register prefetch. Fused 3-pass routing (no-max softmax,
//   logits in LDS [i][n]):
//   P0: s0 = (1/256) sum_i P_i ; P1: d=P.v0 -> lg, e=exp(d), u+=e*P -> s1
//   P2: d+=lg -> s2 -> squash -> out
// Fallback (ws too small): round-3 VALU kernel.

#define ICAPS 256
#define OCAPS 128
#define WS_XC 67108864ull
#define WS_NEED 68157440ull
#define KPAD 20

typedef __attribute__((ext_vector_type(8))) short s16x8;
typedef __attribute__((ext_vector_type(16))) float f32x16;

union u4s8 { unsigned u[4]; s16x8 v; };

__device__ inline unsigned rne_adj(unsigned u) {       // bits + RNE increment
    return u + 0x7FFFu + ((u >> 16) & 1u);
}

// RNE hi/lo split of 8 fp32 -> two packed s16x8 (bf16 pairs), R4/R6 numerics.
__device__ inline void split8(const float* f, s16x8& hi, s16x8& lo) {
    u4s8 H, L;
    #pragma unroll
    for (int c = 0; c < 4; ++c) {
        const unsigned u0 = __float_as_uint(f[2 * c]);
        const unsigned u1 = __float_as_uint(f[2 * c + 1]);
        const unsigned r0 = rne_adj(u0), r1 = rne_adj(u1);
        H.u[c] = __builtin_amdgcn_perm(r1, r0, 0x07060302u);   // {hi16(r1),hi16(r0)}
        const float h0 = __uint_as_float(r0 & 0xFFFF0000u);
        const float h1 = __uint_as_float(r1 & 0xFFFF0000u);
        const unsigned l0 = rne_adj(__float_as_uint(f[2 * c] - h0));      // exact resid
        const unsigned l1 = rne_adj(__float_as_uint(f[2 * c + 1] - h1));  // then RNE
        L.u[c] = __builtin_amdgcn_perm(l1, l0, 0x07060302u);
    }
    hi = H.v; lo = L.v;
}

// ---------------- prep: coalesced read + LDS transpose + split ----------------
// w tiles: gid 0..32767 (= o*256+i); x tiles: gid 32768..33279 (= nh*256+i).
__global__ __launch_bounds__(512)
void caps_prep(const float* __restrict__ x, const float* __restrict__ w,
               unsigned char* __restrict__ ws) {
    __shared__ float T[8][32 * KPAD];     // per-wave 2.5 KB transpose buffer
    const int wv = threadIdx.x >> 6, lane = threadIdx.x & 63;
    const int gid = blockIdx.x * 8 + wv;
    float f[8];
    s16x8 hi, lo;

    if (gid < 32768) {
        // coalesced: wave reads its whole 2KB tile (512 floats) contiguously
        const float* src = w + (size_t)gid * 512 + lane * 8;
        const float4 a = *(const float4*)src;
        const float4 b = *(const float4*)(src + 4);
        const float v[8] = {a.x, a.y, a.z, a.w, b.x, b.y, b.z, b.w};
        // element j: k = lane>>2 (const), l = (lane&3)*8 + j  -> T[l][k]
        {
            float* Tw = &T[wv][0];
            const int k = lane >> 2, l0 = (lane & 3) * 8;
            #pragma unroll
            for (int j = 0; j < 8; ++j) Tw[(l0 + j) * KPAD + k] = v[j];
        }
        __syncthreads();
        // fragment read: l = lane&31, k = kb..kb+7 (contiguous -> 2x b128)
        {
            const float* rd = &T[wv][(lane & 31) * KPAD + (lane >> 5) * 8];
            const float4 ra = *(const float4*)rd;
            const float4 rb = *(const float4*)(rd + 4);
            f[0] = ra.x; f[1] = ra.y; f[2] = ra.z; f[3] = ra.w;
            f[4] = rb.x; f[5] = rb.y; f[6] = rb.z; f[7] = rb.w;
        }
        split8(f, hi, lo);
        s16x8* WC = (s16x8*)ws;
        WC[(size_t)gid * 128 + lane] = hi;        // 1KB coalesced
        WC[(size_t)gid * 128 + 64 + lane] = lo;   // 1KB coalesced
    } else if (gid < 33280) {
        const int id = gid - 32768;
        const int nh = id >> 8, i = id & 255;
        const int n = lane & 31, kb = (lane >> 5) * 8;
        const float* src = x + ((size_t)(nh * 32 + n) * ICAPS + i) * 16 + kb;
        const float4 a = *(const float4*)src;
        const float4 b = *(const float4*)(src + 4);
        f[0] = a.x; f[1] = a.y; f[2] = a.z; f[3] = a.w;
        f[4] = b.x; f[5] = b.y; f[6] = b.z; f[7] = b.w;
        split8(f, hi, lo);
        s16x8* XC = (s16x8*)(ws + WS_XC);
        XC[(size_t)id * 128 + lane] = hi;
        XC[(size_t)id * 128 + 64 + lane] = lo;
    }
}

// ---------------- main: MFMA routing (R6 structure, block-layout frags) ----------------
__global__ __launch_bounds__(512)
void caps_main(const unsigned char* __restrict__ ws, float* __restrict__ out) {
    __shared__ float lg[ICAPS * 32];      // [i][n] 32 KB
    __shared__ float slab[8 * 1280];      // per-wave u partials (lane stride 20)
    __shared__ float svv[32 * 33];        // s then v
    __shared__ float zz[8 * 32];
    __shared__ float zinv[32];

    const int t = threadIdx.x, wv = t >> 6, lane = t & 63;
    const int o = blockIdx.x & 127, nh = blockIdx.x >> 7;   // o-pairs share an XCD
    const int n = lane & 31, half = lane >> 5;

    // block layout: per tile 128 s16x8 records; hi at +lane, lo at +64+lane
    const s16x8* Wp = (const s16x8*)ws + (size_t)o * ICAPS * 128 + lane;
    const s16x8* Xp = (const s16x8*)(ws + WS_XC) + (size_t)nh * ICAPS * 128 + lane;

    float vr[16];
    const int ibase = wv * 32;

    for (int pass = 0; pass < 3; ++pass) {
        float uacc[16];
        #pragma unroll
        for (int r = 0; r < 16; ++r) uacc[r] = 0.f;
        float z = 0.f;

        // cur/nxt register buffers for a 2-i batch: [ah al bh bl] x 2
        s16x8 C[8], Nx[8];
        {
            const size_t b0 = (size_t)ibase * 128;
            C[0] = Wp[b0];       C[1] = Wp[b0 + 64];
            C[2] = Xp[b0];       C[3] = Xp[b0 + 64];
            C[4] = Wp[b0 + 128]; C[5] = Wp[b0 + 192];
            C[6] = Xp[b0 + 128]; C[7] = Xp[b0 + 192];
        }

        if (pass == 0) {
            f32x16 Pa = {}, Pb = {};
            for (int bb = 0; bb < 16; ++bb) {
                if (bb < 15) {
                    const size_t bn = (size_t)(ibase + 2 * (bb + 1)) * 128;
                    Nx[0] = Wp[bn];       Nx[1] = Wp[bn + 64];
                    Nx[2] = Xp[bn];       Nx[3] = Xp[bn + 64];
                    Nx[4] = Wp[bn + 128]; Nx[5] = Wp[bn + 192];
                    Nx[6] = Xp[bn + 128]; Nx[7] = Xp[bn + 192];
                }
                Pa = __builtin_amdgcn_mfma_f32_32x32x16_bf16(C[1], C[2], Pa, 0, 0, 0);
                Pb = __builtin_amdgcn_mfma_f32_32x32x16_bf16(C[5], C[6], Pb, 0, 0, 0);
                Pa = __builtin_amdgcn_mfma_f32_32x32x16_bf16(C[0], C[3], Pa, 0, 0, 0);
                Pb = __builtin_amdgcn_mfma_f32_32x32x16_bf16(C[4], C[7], Pb, 0, 0, 0);
                Pa = __builtin_amdgcn_mfma_f32_32x32x16_bf16(C[0], C[2], Pa, 0, 0, 0);
                Pb = __builtin_amdgcn_mfma_f32_32x32x16_bf16(C[4], C[6], Pb, 0, 0, 0);
                if (bb < 15) {
                    #pragma unroll
                    for (int j = 0; j < 8; ++j) C[j] = Nx[j];
                }
            }
            #pragma unroll
            for (int r = 0; r < 16; ++r) uacc[r] = Pa[r] + Pb[r];
        } else {
            for (int bb = 0; bb < 16; ++bb) {
                if (bb < 15) {
                    const size_t bn = (size_t)(ibase + 2 * (bb + 1)) * 128;
                    Nx[0] = Wp[bn];       Nx[1] = Wp[bn + 64];
                    Nx[2] = Xp[bn];       Nx[3] = Xp[bn + 64];
                    Nx[4] = Wp[bn + 128]; Nx[5] = Wp[bn + 192];
                    Nx[6] = Xp[bn + 128]; Nx[7] = Xp[bn + 192];
                }
                f32x16 P0 = {}, P1 = {};
                P0 = __builtin_amdgcn_mfma_f32_32x32x16_bf16(C[1], C[2], P0, 0, 0, 0);
                P1 = __builtin_amdgcn_mfma_f32_32x32x16_bf16(C[5], C[6], P1, 0, 0, 0);
                P0 = __builtin_amdgcn_mfma_f32_32x32x16_bf16(C[0], C[3], P0, 0, 0, 0);
                P1 = __builtin_amdgcn_mfma_f32_32x32x16_bf16(C[4], C[7], P1, 0, 0, 0);
                P0 = __builtin_amdgcn_mfma_f32_32x32x16_bf16(C[0], C[2], P0, 0, 0, 0);
                P1 = __builtin_amdgcn_mfma_f32_32x32x16_bf16(C[4], C[6], P1, 0, 0, 0);

                #pragma unroll
                for (int j = 0; j < 2; ++j) {
                    const f32x16& P = j ? P1 : P0;
                    const int i = ibase + bb * 2 + j;
                    float da = P[0] * vr[0];
                    float db = P[8] * vr[8];
                    #pragma unroll
                    for (int r = 1; r < 8; ++r) {
                        da = fmaf(P[r], vr[r], da);
                        db = fmaf(P[r + 8], vr[r + 8], db);
                    }
                    float d = da + db;
                    d += __shfl_xor(d, 32);                 // combine l-halves
                    if (pass == 1) {
                        if (half == 0) lg[i * 32 + n] = d;  // store logits for pass 2
                    } else {
                        d += lg[i * 32 + n];
                    }
                    const float e = __expf(d);
                    z += e;
                    #pragma unroll
                    for (int r = 0; r < 16; ++r) uacc[r] = fmaf(e, P[r], uacc[r]);
                }
                if (bb < 15) {
                    #pragma unroll
                    for (int j = 0; j < 8; ++j) C[j] = Nx[j];
                }
            }
        }

        // ---- cross-wave reduce of u (and z) over 8 waves ----
        #pragma unroll
        for (int c = 0; c < 4; ++c)
            *(float4*)(&slab[wv * 1280 + lane * 20 + c * 4]) =
                make_float4(uacc[4 * c], uacc[4 * c + 1], uacc[4 * c + 2], uacc[4 * c + 3]);
        if (pass > 0 && half == 0) zz[wv * 32 + n] = z;
        __syncthreads();

        #pragma unroll
        for (int hh = 0; hh < 2; ++hh) {
            const int e = t + hh * 512;
            const int lw = e >> 4, r = e & 15;
            float s = 0.f;
            #pragma unroll
            for (int w8 = 0; w8 < 8; ++w8) s += slab[w8 * 1280 + lw * 20 + r];
            const int nn = lw & 31, ll = (r & 3) + 8 * (r >> 2) + 4 * (lw >> 5);
            svv[nn * 33 + ll] = s;
        }
        if (t < 32) {
            if (pass == 0) zinv[t] = 1.0f / 256.0f;
            else {
                float zs = 0.f;
                #pragma unroll
                for (int w8 = 0; w8 < 8; ++w8) zs += zz[w8 * 32 + t];
                zinv[t] = 1.0f / zs;
            }
        }
        __syncthreads();

        // ---- squash (and output on last pass) ----
        {
            const int nq = t >> 4, sub = t & 15;
            const float a = svv[nq * 33 + sub] * zinv[nq];
            const float b = svv[nq * 33 + sub + 16] * zinv[nq];
            float sq = a * a + b * b;
            #pragma unroll
            for (int m = 1; m < 16; m <<= 1) sq += __shfl_xor(sq, m, 16);
            const float sc = sqrtf(sq) / (1.0f + sq);
            if (pass == 2) {
                const int ng = nh * 32 + nq;
                out[((size_t)ng * OCAPS + o) * 32 + sub] = a * sc;
                out[((size_t)ng * OCAPS + o) * 32 + sub + 16] = b * sc;
            } else {
                svv[nq * 33 + sub] = a * sc;
                svv[nq * 33 + sub + 16] = b * sc;
            }
        }
        if (pass < 2) {
            __syncthreads();
            #pragma unroll
            for (int r = 0; r < 16; ++r) {
                const int l = (r & 3) + 8 * (r >> 2) + 4 * half;
                vr[r] = svv[n * 33 + l];
            }
        }
    }
}

// ---------------- fallback (round-3 kernel, no ws needed) ----------------
#define KLEN  16
#define LLEN  32
#define TN    16
#define LGS   257
#define XROW  20
#define XIST  (TN * XROW + 4)
#define SVS   33
#define RBS   33
#define NSTG  32
#define NSTEP (ICAPS / NSTG)

__global__ __launch_bounds__(512, 2)
void caps_route_fb(const float* __restrict__ xg_all,
                   const float* __restrict__ wg_all,
                   float* __restrict__ out) {
    __shared__ float lg[TN * LGS];
    __shared__ float xt[NSTG * XIST];
    __shared__ float sv[TN * SVS];
    __shared__ float zz[8][TN];
    __shared__ float zinv[TN];

    const int t   = threadIdx.x;
    const int o   = blockIdx.x & 127;
    const int n0  = (blockIdx.x >> 7) * TN;
    const int isp = t >> 4;
    const int lb  = (t >> 2) & 3;
    const int nb  = t & 3;
    const int l0  = lb * 8;

    const float* xg = xg_all + (size_t)n0 * ICAPS * KLEN;
    const float* wg = wg_all + (size_t)o * ICAPS * KLEN * LLEN;

    for (int pass = 0; pass < 3; ++pass) {
        float u[4][8];
        float zq[4] = {0.f, 0.f, 0.f, 0.f};
        #pragma unroll
        for (int q = 0; q < 4; ++q)
            #pragma unroll
            for (int r = 0; r < 8; ++r) u[q][r] = 0.f;

        for (int st = 0; st < NSTEP; ++st) {
            const int i0 = st * NSTG;
            __syncthreads();
            #pragma unroll
            for (int j = 0; j < 4; ++j) {
                const int g   = j * 512 + t;
                const int nn  = g >> 7;
                const int rem = g & 127;
                const int il  = rem >> 2;
                const int k4c = rem & 3;
                *(float4*)(&xt[il * XIST + nn * XROW + k4c * 4]) =
                    *(const float4*)(xg + (size_t)(nn * ICAPS + i0 + il) * KLEN + k4c * 4);
            }
            __syncthreads();

            const int i = i0 + isp;
            const float* wp = wg + (size_t)i * (KLEN * LLEN) + l0;
            const float* xp = &xt[isp * XIST];
            float P[4][8];
            #pragma unroll
            for (int q = 0; q < 4; ++q)
                #pragma unroll
                for (int r = 0; r < 8; ++r) P[q][r] = 0.f;

            #pragma unroll
            for (int k4 = 0; k4 < 4; ++k4) {
                float xq[4][4];
                #pragma unroll
                for (int q = 0; q < 4; ++q)
                    *(float4*)(&xq[q][0]) = *(const float4*)(xp + (nb + 4 * q) * XROW + k4 * 4);
                #pragma unroll
                for (int kk = 0; kk < 4; ++kk) {
                    const int k = k4 * 4 + kk;
                    const float4 wa = *(const float4*)(wp + k * LLEN);
                    const float4 wb = *(const float4*)(wp + k * LLEN + 4);
                    #pragma unroll
                    for (int q = 0; q < 4; ++q) {
                        const float xv = xq[q][kk];
                        P[q][0] = fmaf(xv, wa.x, P[q][0]);
                        P[q][1] = fmaf(xv, wa.y, P[q][1]);
                        P[q][2] = fmaf(xv, wa.z, P[q][2]);
                        P[q][3] = fmaf(xv, wa.w, P[q][3]);
                        P[q][4] = fmaf(xv, wb.x, P[q][4]);
                        P[q][5] = fmaf(xv, wb.y, P[q][5]);
                        P[q][6] = fmaf(xv, wb.z, P[q][6]);
                        P[q][7] = fmaf(xv, wb.w, P[q][7]);
                    }
                }
            }

            if (pass == 0) {
                #pragma unroll
                for (int q = 0; q < 4; ++q)
                    #pragma unroll
                    for (int r = 0; r < 8; ++r) u[q][r] += P[q][r];
            } else {
                #pragma unroll
                for (int q = 0; q < 4; ++q) {
                    const float* vp = &sv[(nb + 4 * q) * SVS + l0];
                    float d = P[q][0] * vp[0] + P[q][1] * vp[1] + P[q][2] * vp[2] + P[q][3] * vp[3]
                            + P[q][4] * vp[4] + P[q][5] * vp[5] + P[q][6] * vp[6] + P[q][7] * vp[7];
                    d += __shfl_xor(d, 4);
                    d += __shfl_xor(d, 8);
                    float lnew = d;
                    if (pass == 2) lnew += lg[(nb + 4 * q) * LGS + i];
                    else if (lb == 0) lg[(nb + 4 * q) * LGS + i] = lnew;
                    const float e = __expf(lnew);
                    zq[q] += e;
                    #pragma unroll
                    for (int r = 0; r < 8; ++r) u[q][r] = fmaf(e, P[q][r], u[q][r]);
                }
            }
        }

        #pragma unroll
        for (int q = 0; q < 4; ++q) {
            #pragma unroll
            for (int r = 0; r < 8; ++r) {
                float v = u[q][r];
                v += __shfl_xor(v, 16);
                v += __shfl_xor(v, 32);
                u[q][r] = v;
            }
            float zv = zq[q];
            zv += __shfl_xor(zv, 16);
            zv += __shfl_xor(zv, 32);
            zq[q] = zv;
        }
        __syncthreads();
        {
            const int wvv = t >> 6, lane = t & 63;
            if (lane < 16) {
                float* rb = &xt[wvv * (16 * RBS) + lane * RBS];
                #pragma unroll
                for (int q = 0; q < 4; ++q)
                    #pragma unroll
                    for (int r = 0; r < 8; ++r) rb[q * 8 + r] = u[q][r];
            }
            if (pass > 0 && lane < 4) {
                #pragma unroll
                for (int q = 0; q < 4; ++q) zz[wvv][lane + 4 * q] = zq[q];
            }
        }
        __syncthreads();
        {
            const int low4 = t >> 5, qr = t & 31;
            const int qq = qr >> 3, rr = qr & 7;
            const int lbb = low4 >> 2, nbb = low4 & 3;
            float ssum = 0.f;
            #pragma unroll
            for (int w8 = 0; w8 < 8; ++w8) ssum += xt[w8 * (16 * RBS) + low4 * RBS + qr];
            sv[(nbb + 4 * qq) * SVS + lbb * 8 + rr] = ssum;
        }
        if (t < TN) {
            if (pass == 0) zinv[t] = 1.0f / 256.0f;
            else {
                float zs = 0.f;
                #pragma unroll
                for (int w8 = 0; w8 < 8; ++w8) zs += zz[w8][t];
                zinv[t] = 1.0f / zs;
            }
        }
        __syncthreads();
        {
            const int nn = t >> 5, l = t & 31;
            const float val = sv[nn * SVS + l] * zinv[nn];
            float sq = val * val;
            #pragma unroll
            for (int m = 1; m < 32; m <<= 1) sq += __shfl_xor(sq, m, 32);
            const float sc = sqrtf(sq) / (1.0f + sq);
            if (pass == 2)
                out[((size_t)(n0 + nn) * OCAPS + o) * LLEN + l] = val * sc;
            else
                sv[nn * SVS + l] = val * sc;
        }
    }
}

extern "C" void kernel_launch(void* const* d_in, const int* in_sizes, int n_in,
                              void* d_out, int out_size, void* d_ws, size_t ws_size,
                              hipStream_t stream) {
    const float* x = (const float*)d_in[0];   // [64,256,16]
    const float* w = (const float*)d_in[1];   // [128,256,16,32]
    float* outp = (float*)d_out;              // [64,128,32]
    if (ws_size >= WS_NEED) {
        caps_prep<<<dim3(4160), dim3(512), 0, stream>>>(x, w, (unsigned char*)d_ws);
        caps_main<<<dim3(256), dim3(512), 0, stream>>>((const unsigned char*)d_ws, outp);
    } else {
        caps_route_fb<<<dim3(512), dim3(512), 0, stream>>>(x, w, outp);
    }
}